// Round 2
// baseline (672.553 us; speedup 1.0000x reference)
//
#include <hip/hip_runtime.h>
#include <hip/hip_bf16.h>

typedef __attribute__((ext_vector_type(8))) short bf16x8;
typedef __attribute__((ext_vector_type(4))) float f32x4;
typedef unsigned short ushort_t;

#define AS1 __attribute__((address_space(1)))
#define AS3 __attribute__((address_space(3)))

__device__ __forceinline__ void gload_lds16(const void* g, void* l) {
    __builtin_amdgcn_global_load_lds((const AS1 void*)g, (AS3 void*)l, 16, 0, 0);
}

__device__ __forceinline__ ushort_t f2b(float f) {
    unsigned u = __builtin_bit_cast(unsigned, f);
    unsigned r = (u + 0x7FFFu + ((u >> 16) & 1u)) >> 16;
    return (ushort_t)r;
}

__device__ __forceinline__ float b2f(short s) {
    unsigned v = ((unsigned)(ushort_t)s) << 16;
    return __builtin_bit_cast(float, v);
}

__device__ __forceinline__ int swz2(int row) {
    return (((row & 7) ^ ((row >> 3) & 7)) << 4);
}

// ---------------- convert x (fp32 -> bf16) ----------------
__global__ __launch_bounds__(256) void convert_x_kernel(const float* __restrict__ in,
                                                        ushort_t* __restrict__ out, int n4) {
    int i = blockIdx.x * blockDim.x + threadIdx.x;
    if (i < n4) {
        float4 f = ((const float4*)in)[i];
        ushort4 u;
        u.x = f2b(f.x); u.y = f2b(f.y); u.z = f2b(f.z); u.w = f2b(f.w);
        ((ushort4*)out)[i] = u;
    }
}

// ---------------- transpose + convert weight: W[K][N] fp32 -> WT[N][K] bf16 ----------------
__global__ __launch_bounds__(256) void transpose_w_kernel(const float* __restrict__ W,
                                                          ushort_t* __restrict__ WT) {
    __shared__ float t[32][33];
    int n0 = blockIdx.x * 32, k0 = blockIdx.y * 32;
    int tx = threadIdx.x, ty = threadIdx.y; // block (32,8)
    for (int i = 0; i < 4; ++i)
        t[ty + i * 8][tx] = W[(size_t)(k0 + ty + i * 8) * 1024 + n0 + tx];
    __syncthreads();
    for (int i = 0; i < 4; ++i)
        WT[(size_t)(n0 + ty + i * 8) * 1024 + k0 + tx] = f2b(t[tx][ty + i * 8]);
}

// ---------------- bf16 MFMA GEMM, 2-phase dbuf global_load_lds ----------------
// C[8192][1024] = A[8192][1024] @ BT[1024][1024]^T, BT is [N][K].
template <int OUT_BF16>
__global__ __launch_bounds__(256) void gemm_kernel(const ushort_t* __restrict__ A,
                                                   const ushort_t* __restrict__ BT,
                                                   ushort_t* __restrict__ Cb,
                                                   float* __restrict__ Cf,
                                                   const float* __restrict__ bias) {
    const int K = 1024;
    __shared__ ushort_t As[2 * 128 * 32];
    __shared__ ushort_t Bs[2 * 128 * 32];
    int tid = threadIdx.x;
    int wid = tid >> 6, lane = tid & 63;
    int g = lane >> 4, lr = lane & 15;
    int m0 = blockIdx.x * 128, n0 = blockIdx.y * 128;
    int wm = wid >> 1, wn = wid & 1;

    f32x4 acc[4][4] = {};

    // staging geometry: chunk = 1 KB = 16 rows x 64 B; wave w owns chunks 2w, 2w+1
    int c0 = wid * 2;
    int lrow = lane >> 2;                              // row within chunk
    int lcol = ((lane & 3) ^ ((lane >> 3) & 3)) * 8;   // pre-swizzled source col (elems)
    const ushort_t* Ag0 = A  + (size_t)(m0 + c0 * 16 + lrow) * K + lcol;
    const ushort_t* Ag1 = A  + (size_t)(m0 + c0 * 16 + 16 + lrow) * K + lcol;
    const ushort_t* Bg0 = BT + (size_t)(n0 + c0 * 16 + lrow) * K + lcol;
    const ushort_t* Bg1 = BT + (size_t)(n0 + c0 * 16 + 16 + lrow) * K + lcol;

    int swzA = ((lr >> 1) & 3) << 4;   // fragment-read byte XOR

    auto stage = [&](int bufi, int kt) {
        char* a0 = (char*)As + bufi * 8192 + c0 * 1024;
        char* b0 = (char*)Bs + bufi * 8192 + c0 * 1024;
        gload_lds16(Ag0 + kt * 32, a0);
        gload_lds16(Ag1 + kt * 32, a0 + 1024);
        gload_lds16(Bg0 + kt * 32, b0);
        gload_lds16(Bg1 + kt * 32, b0 + 1024);
    };

    stage(0, 0);
    __syncthreads();
    int buf = 0;
    for (int kt = 0; kt < K / 32; ++kt) {
        if (kt + 1 < K / 32) stage(buf ^ 1, kt + 1);
        const char* ab = (const char*)As + buf * 8192;
        const char* bb = (const char*)Bs + buf * 8192;
        bf16x8 af[4], bfr[4];
#pragma unroll
        for (int m = 0; m < 4; ++m) {
            int row = wm * 64 + m * 16 + lr;
            af[m] = *(const bf16x8*)(ab + row * 64 + ((g * 16) ^ swzA));
        }
#pragma unroll
        for (int n = 0; n < 4; ++n) {
            int row = wn * 64 + n * 16 + lr;
            bfr[n] = *(const bf16x8*)(bb + row * 64 + ((g * 16) ^ swzA));
        }
#pragma unroll
        for (int m = 0; m < 4; ++m)
#pragma unroll
            for (int n = 0; n < 4; ++n)
                acc[m][n] = __builtin_amdgcn_mfma_f32_16x16x32_bf16(af[m], bfr[n], acc[m][n], 0, 0, 0);
        __syncthreads();
        buf ^= 1;
    }

#pragma unroll
    for (int m = 0; m < 4; ++m)
#pragma unroll
        for (int n = 0; n < 4; ++n) {
            int row0 = m0 + wm * 64 + m * 16 + g * 4;
            int col  = n0 + wn * 64 + n * 16 + lr;
#pragma unroll
            for (int r = 0; r < 4; ++r) {
                float v = acc[m][n][r];
                if (OUT_BF16)
                    Cb[(size_t)(row0 + r) * 1024 + col] = f2b(v);
                else
                    Cf[(size_t)(row0 + r) * 1024 + col] = v + bias[col];
            }
        }
}

// ---------------- fused attention ----------------
// grid (32 qtiles, 16 heads, 4 batch), block 256 (4 waves, 16 q-rows each)
__global__ __launch_bounds__(256) void attn_kernel(const ushort_t* __restrict__ Qg,
                                                   const ushort_t* __restrict__ Kg,
                                                   const ushort_t* __restrict__ Vg,
                                                   float* __restrict__ Pout,
                                                   ushort_t* __restrict__ Oout) {
    const int S = 2048, D = 1024;
    int b = blockIdx.z, h = blockIdx.y;
    int qt = (int)blockIdx.x;
    int q0 = qt * 64;
    int tid = threadIdx.x, wid = tid >> 6, lane = tid & 63;
    int g = lane >> 4, lr = lane & 15;

    __shared__ ushort_t Ks[2][64 * 64];
    __shared__ ushort_t Vt[64 * 64];
    __shared__ ushort_t Pb[64 * 64];

    const ushort_t* Qb = Qg + (size_t)b * S * D + (size_t)h * 64;
    const ushort_t* Kb = Kg + (size_t)b * S * D + (size_t)h * 64;
    const ushort_t* Vb = Vg + (size_t)b * S * D + (size_t)h * 64;
    float* Pbase = Pout + (((size_t)b * 16 + h) * S + q0) * S;

    // K staging geometry: chunk = 1 KB = 8 rows x 128 B; wave owns chunks 2w, 2w+1
    int krow = lane >> 3;                  // 0..7
    int kcol = ((lane & 7) ^ krow) * 8;    // pre-swizzled source col (elems)
    int kc0 = wid * 2;
    const ushort_t* Kg0 = Kb + (size_t)(kc0 * 8 + krow) * D + kcol;
    const ushort_t* Kg1 = Kb + (size_t)(kc0 * 8 + 8 + krow) * D + kcol;

    auto stageK = [&](int bufi, int tt) {
        char* l0 = (char*)&Ks[bufi][0] + kc0 * 1024;
        gload_lds16(Kg0 + (size_t)tt * 64 * D, l0);
        gload_lds16(Kg1 + (size_t)tt * 64 * D, l0 + 1024);
    };

    int swzk = (lr & 7) << 4;   // Ks fragment-read XOR (row = nb*16+lr)

    // Q fragments (held in regs)
    bf16x8 qf[2];
    {
        int qrow = q0 + wid * 16 + lr;
#pragma unroll
        for (int kc = 0; kc < 2; ++kc)
            qf[kc] = *(const bf16x8*)(Qb + (size_t)qrow * D + kc * 32 + g * 8);
    }

    float m[4], l[4];
#pragma unroll
    for (int r = 0; r < 4; ++r) { m[r] = -1e30f; l[r] = 0.f; }

    // ---- phase 1: row max + sumexp ----
    stageK(0, 0);
    __syncthreads();
    int buf = 0;
    for (int tt = 0; tt <= qt; ++tt) {
        if (tt < qt) stageK(buf ^ 1, tt + 1);
        const char* ksb = (const char*)&Ks[buf][0];
        float sv[4][4];
#pragma unroll
        for (int nb = 0; nb < 4; ++nb) {
            f32x4 s = {};
#pragma unroll
            for (int kc = 0; kc < 2; ++kc) {
                bf16x8 kf = *(const bf16x8*)(ksb + (nb * 16 + lr) * 128 + ((kc * 64 + g * 16) ^ swzk));
                s = __builtin_amdgcn_mfma_f32_16x16x32_bf16(qf[kc], kf, s, 0, 0, 0);
            }
#pragma unroll
            for (int r = 0; r < 4; ++r) sv[nb][r] = s[r] * 0.125f;
        }
        if (tt == qt) {
            int qrow = wid * 16 + g * 4;   // local q row base
#pragma unroll
            for (int nb = 0; nb < 4; ++nb)
#pragma unroll
                for (int r = 0; r < 4; ++r)
                    if (nb * 16 + lr > qrow + r) sv[nb][r] = -1e30f;
        }
#pragma unroll
        for (int r = 0; r < 4; ++r) {
            float mx = fmaxf(fmaxf(sv[0][r], sv[1][r]), fmaxf(sv[2][r], sv[3][r]));
#pragma unroll
            for (int msk = 1; msk < 16; msk <<= 1) mx = fmaxf(mx, __shfl_xor(mx, msk));
            float mnew = fmaxf(m[r], mx);
            float ssum = 0.f;
#pragma unroll
            for (int nb = 0; nb < 4; ++nb) {
                float sval = sv[nb][r];
                ssum += (sval > -1e29f) ? __expf(sval - mnew) : 0.f;
            }
#pragma unroll
            for (int msk = 1; msk < 16; msk <<= 1) ssum += __shfl_xor(ssum, msk);
            l[r] = l[r] * __expf(m[r] - mnew) + ssum;
            m[r] = mnew;
        }
        __syncthreads();
        buf ^= 1;
    }

    float invl[4];
#pragma unroll
    for (int r = 0; r < 4; ++r) invl[r] = 1.0f / l[r];

    f32x4 Oacc[4] = {};

    int vsr = tid >> 2;           // 0..63
    int vsc = (tid & 3) * 16;     // 0,16,32,48

    // ---- phase 2: write P + accumulate O ----
    stageK(buf, 0);
    bf16x8 v0 = *(const bf16x8*)(Vb + (size_t)vsr * D + vsc);
    bf16x8 v1 = *(const bf16x8*)(Vb + (size_t)vsr * D + vsc + 8);
    __syncthreads();
    for (int tt = 0; tt <= qt; ++tt) {
        // V -> Vt (transposed, swizzled); prev PV done (barrier2 of prev iter)
#pragma unroll
        for (int j = 0; j < 8; ++j) {
            int d0 = vsc + j, d1 = vsc + 8 + j;
            *(ushort_t*)((char*)Vt + ((d0 * 128 + vsr * 2) ^ swz2(d0))) = (ushort_t)v0[j];
            *(ushort_t*)((char*)Vt + ((d1 * 128 + vsr * 2) ^ swz2(d1))) = (ushort_t)v1[j];
        }
        if (tt < qt) {
            stageK(buf ^ 1, tt + 1);
            v0 = *(const bf16x8*)(Vb + (size_t)((tt + 1) * 64 + vsr) * D + vsc);
            v1 = *(const bf16x8*)(Vb + (size_t)((tt + 1) * 64 + vsr) * D + vsc + 8);
        }
        const char* ksb = (const char*)&Ks[buf][0];
#pragma unroll
        for (int nb = 0; nb < 4; ++nb) {
            f32x4 s = {};
#pragma unroll
            for (int kc = 0; kc < 2; ++kc) {
                bf16x8 kf = *(const bf16x8*)(ksb + (nb * 16 + lr) * 128 + ((kc * 64 + g * 16) ^ swzk));
                s = __builtin_amdgcn_mfma_f32_16x16x32_bf16(qf[kc], kf, s, 0, 0, 0);
            }
            int qrow = wid * 16 + g * 4;
#pragma unroll
            for (int r = 0; r < 4; ++r) {
                float p;
                if (tt == qt && (nb * 16 + lr > qrow + r)) p = 0.f;
                else p = __expf(s[r] * 0.125f - m[r]) * invl[r];
                int prow = qrow + r;
                int pbyte = (prow * 128 + (nb * 16 + lr) * 2) ^ swz2(prow);
                *(ushort_t*)((char*)Pb + pbyte) = f2b(p);
            }
        }
        __syncthreads();   // Pb + Vt visible; K prefetch drained

        // PV MFMA
        int xp = swz2(wid * 16 + lr);
#pragma unroll
        for (int kc = 0; kc < 2; ++kc) {
            bf16x8 pf = *(const bf16x8*)((char*)Pb + (wid * 16 + lr) * 128 + ((kc * 64 + g * 16) ^ xp));
#pragma unroll
            for (int nb = 0; nb < 4; ++nb) {
                bf16x8 vf = *(const bf16x8*)((char*)Vt + (nb * 16 + lr) * 128 + ((kc * 64 + g * 16) ^ swz2(nb * 16 + lr)));
                Oacc[nb] = __builtin_amdgcn_mfma_f32_16x16x32_bf16(pf, vf, Oacc[nb], 0, 0, 0);
            }
        }

        // coalesced P global write (fp32) from bf16 Pb
        {
            int xr = swz2(vsr);
            bf16x8 p0 = *(const bf16x8*)((char*)Pb + vsr * 128 + ((vsc * 2) ^ xr));
            bf16x8 p1 = *(const bf16x8*)((char*)Pb + vsr * 128 + ((vsc * 2 + 16) ^ xr));
            float* dst = Pbase + (size_t)vsr * S + tt * 64 + vsc;
            float4 w;
            w.x = b2f(p0[0]); w.y = b2f(p0[1]); w.z = b2f(p0[2]); w.w = b2f(p0[3]);
            ((float4*)dst)[0] = w;
            w.x = b2f(p0[4]); w.y = b2f(p0[5]); w.z = b2f(p0[6]); w.w = b2f(p0[7]);
            ((float4*)dst)[1] = w;
            w.x = b2f(p1[0]); w.y = b2f(p1[1]); w.z = b2f(p1[2]); w.w = b2f(p1[3]);
            ((float4*)dst)[2] = w;
            w.x = b2f(p1[4]); w.y = b2f(p1[5]); w.z = b2f(p1[6]); w.w = b2f(p1[7]);
            ((float4*)dst)[3] = w;
        }
        __syncthreads();   // Pb + Vt consumed
        buf ^= 1;
    }

    // zero-fill strictly-upper tiles
    float4 z = {0.f, 0.f, 0.f, 0.f};
    for (int tt = qt + 1; tt < 32; ++tt) {
        float* dst = Pbase + (size_t)vsr * S + tt * 64 + vsc;
#pragma unroll
        for (int j = 0; j < 4; ++j) ((float4*)dst)[j] = z;
    }

    // write O (bf16) as [B,S,H*Dh]
#pragma unroll
    for (int nb = 0; nb < 4; ++nb)
#pragma unroll
        for (int r = 0; r < 4; ++r) {
            int q = q0 + wid * 16 + g * 4 + r;
            int d = nb * 16 + lr;
            Oout[((size_t)b * S + q) * D + h * 64 + d] = f2b(Oacc[nb][r]);
        }
}

extern "C" void kernel_launch(void* const* d_in, const int* in_sizes, int n_in,
                              void* d_out, int out_size, void* d_ws, size_t ws_size,
                              hipStream_t stream) {
    const float* x  = (const float*)d_in[0];
    const float* Wq = (const float*)d_in[1];
    const float* Wk = (const float*)d_in[2];
    const float* Wv = (const float*)d_in[3];
    const float* Wo = (const float*)d_in[4];
    const float* bo = (const float*)d_in[5];

    float* out  = (float*)d_out;
    float* Pout = out + (size_t)8388608; // attn_probs region

    char* ws = (char*)d_ws;
    ushort_t* xb    = (ushort_t*)(ws);
    ushort_t* wqb   = (ushort_t*)(ws + 16777216);
    ushort_t* wkb   = (ushort_t*)(ws + 18874368);
    ushort_t* wvb   = (ushort_t*)(ws + 20971520);
    ushort_t* wob   = (ushort_t*)(ws + 23068672);
    ushort_t* Qw    = (ushort_t*)(ws + 25165824);
    ushort_t* Kw    = (ushort_t*)(ws + 41943040);
    ushort_t* Vw    = (ushort_t*)(ws + 58720256);
    ushort_t* attnb = (ushort_t*)(ws + 75497472);

    // 1. dtype conversions
    convert_x_kernel<<<8192, 256, 0, stream>>>(x, xb, 2097152);
    transpose_w_kernel<<<dim3(32, 32), dim3(32, 8), 0, stream>>>(Wq, wqb);
    transpose_w_kernel<<<dim3(32, 32), dim3(32, 8), 0, stream>>>(Wk, wkb);
    transpose_w_kernel<<<dim3(32, 32), dim3(32, 8), 0, stream>>>(Wv, wvb);
    transpose_w_kernel<<<dim3(32, 32), dim3(32, 8), 0, stream>>>(Wo, wob);

    // 2. QKV projections
    gemm_kernel<1><<<dim3(64, 8), 256, 0, stream>>>(xb, wqb, Qw, nullptr, nullptr);
    gemm_kernel<1><<<dim3(64, 8), 256, 0, stream>>>(xb, wkb, Kw, nullptr, nullptr);
    gemm_kernel<1><<<dim3(64, 8), 256, 0, stream>>>(xb, wvb, Vw, nullptr, nullptr);

    // 3. attention (writes attn_probs fp32 + context bf16)
    attn_kernel<<<dim3(32, 16, 4), 256, 0, stream>>>(Qw, Kw, Vw, Pout, attnb);

    // 4. output projection + bias (fp32 out)
    gemm_kernel<0><<<dim3(64, 8), 256, 0, stream>>>(attnb, wob, nullptr, out, bo);
}